// Round 1
// baseline (279.248 us; speedup 1.0000x reference)
//
#include <hip/hip_runtime.h>
#include <math.h>

#define N_ 64
#define L_ 256
#define D_ 1024
#define M_ 128
#define KC 32
#define LDT 68   // 64 + 4 pad, keeps 16B alignment for float4 LDS reads

typedef float f4 __attribute__((ext_vector_type(4)));

// ---------------- row sum-of-squares (one wave per row, D=1024) ----------------
__global__ __launch_bounds__(256) void ssq_kernel(const float* __restrict__ in,
                                                  float* __restrict__ out, int rows) {
    int w = threadIdx.x >> 6;
    int lane = threadIdx.x & 63;
    int row = blockIdx.x * 4 + w;
    if (row >= rows) return;
    const f4* p = (const f4*)(in + (size_t)row * D_);
    float s = 0.f;
#pragma unroll
    for (int rep = 0; rep < 4; ++rep) {
        f4 v = p[rep * 64 + lane];
        s += v[0]*v[0] + v[1]*v[1] + v[2]*v[2] + v[3]*v[3];
    }
#pragma unroll
    for (int off = 32; off; off >>= 1) s += __shfl_down(s, off);
    if (lane == 0) out[row] = s;
}

// ---------------- mask row sums: S[n] = sum_l mask[n,l] ----------------
__global__ __launch_bounds__(64) void masksum_kernel(const int* __restrict__ mask,
                                                     float* __restrict__ S) {
    int n = blockIdx.x;
    int lane = threadIdx.x;
    int s = 0;
#pragma unroll
    for (int rep = 0; rep < 4; ++rep) s += mask[n * L_ + rep * 64 + lane];
#pragma unroll
    for (int off = 32; off; off >>= 1) s += __shfl_down(s, off);
    if (lane == 0) S[n] = (float)s;
}

// ---------------- ed_sums raw: sum_l sqrt(max(sqx+sqy-2*x.y,0))*mask ----------------
// one block = (n, 64 l-rows, 64 m-cols); 256 threads, 4x4 micro-tile
__global__ __launch_bounds__(256) void edxy_kernel(const float* __restrict__ x,
                                                   const float* __restrict__ y,
                                                   const float* __restrict__ sqx,
                                                   const float* __restrict__ sqy,
                                                   const int* __restrict__ mask,
                                                   float* __restrict__ ed_raw) {
    __shared__ __align__(16) float As[KC * LDT];
    __shared__ __align__(16) float Bs[KC * LDT];
    __shared__ float red[64];
    int tid = threadIdx.x;
    int n  = blockIdx.z;
    int l0 = blockIdx.y * 64;
    int m0 = blockIdx.x * 64;
    int ty = tid >> 4, tx = tid & 15;
    int r = tid >> 3, c4 = (tid & 7) * 4;

    const float* xa = x + ((size_t)n * L_ + l0) * D_;
    const float* yb = y + (size_t)m0 * D_;

    float acc[4][4] = {};
    for (int kc = 0; kc < D_; kc += KC) {
        __syncthreads();
        f4 a0 = *(const f4*)(xa + (size_t)r * D_ + kc + c4);
        f4 a1 = *(const f4*)(xa + (size_t)(r + 32) * D_ + kc + c4);
        f4 b0 = *(const f4*)(yb + (size_t)r * D_ + kc + c4);
        f4 b1 = *(const f4*)(yb + (size_t)(r + 32) * D_ + kc + c4);
#pragma unroll
        for (int j = 0; j < 4; ++j) {
            As[(c4 + j) * LDT + r]      = a0[j];
            As[(c4 + j) * LDT + r + 32] = a1[j];
            Bs[(c4 + j) * LDT + r]      = b0[j];
            Bs[(c4 + j) * LDT + r + 32] = b1[j];
        }
        __syncthreads();
#pragma unroll
        for (int k = 0; k < KC; ++k) {
            f4 a = *(const f4*)&As[k * LDT + ty * 4];
            f4 b = *(const f4*)&Bs[k * LDT + tx * 4];
#pragma unroll
            for (int i = 0; i < 4; ++i)
#pragma unroll
                for (int j = 0; j < 4; ++j)
                    acc[i][j] = fmaf(a[i], b[j], acc[i][j]);
        }
    }

    float colsum[4] = {0.f, 0.f, 0.f, 0.f};
#pragma unroll
    for (int i = 0; i < 4; ++i) {
        int l = l0 + ty * 4 + i;
        float sx = sqx[n * L_ + l];
        float mf = (float)mask[n * L_ + l];
#pragma unroll
        for (int j = 0; j < 4; ++j) {
            int m = m0 + tx * 4 + j;
            float raw = sx + sqy[m] - 2.f * acc[i][j];
            float d = raw > 0.f ? sqrtf(raw) : 0.f;
            colsum[j] += d * mf;
        }
    }
    if (tid < 64) red[tid] = 0.f;
    __syncthreads();
#pragma unroll
    for (int j = 0; j < 4; ++j) atomicAdd(&red[tx * 4 + j], colsum[j]);
    __syncthreads();
    if (tid < 64) atomicAdd(&ed_raw[n * M_ + m0 + tid], red[tid]);
}

// ---------------- ed_q raw: sum_{ij} sqrt(max(sqi+sqj-2*xi.xj,0))*mi*mj ----------------
__device__ const int TI_[10] = {0, 0, 0, 0, 1, 1, 1, 2, 2, 3};
__device__ const int TJ_[10] = {0, 1, 2, 3, 1, 2, 3, 2, 3, 3};

__global__ __launch_bounds__(256) void edxx_kernel(const float* __restrict__ x,
                                                   const float* __restrict__ sqx,
                                                   const int* __restrict__ mask,
                                                   float* __restrict__ edq) {
    __shared__ __align__(16) float As[KC * LDT];
    __shared__ __align__(16) float Bs[KC * LDT];
    int tid = threadIdx.x;
    int p = blockIdx.x;
    int n = blockIdx.y;
    int i0 = TI_[p] * 64, j0 = TJ_[p] * 64;
    int ty = tid >> 4, tx = tid & 15;
    int r = tid >> 3, c4 = (tid & 7) * 4;

    const float* xa = x + ((size_t)n * L_ + i0) * D_;
    const float* xb = x + ((size_t)n * L_ + j0) * D_;

    float acc[4][4] = {};
    for (int kc = 0; kc < D_; kc += KC) {
        __syncthreads();
        f4 a0 = *(const f4*)(xa + (size_t)r * D_ + kc + c4);
        f4 a1 = *(const f4*)(xa + (size_t)(r + 32) * D_ + kc + c4);
        f4 b0 = *(const f4*)(xb + (size_t)r * D_ + kc + c4);
        f4 b1 = *(const f4*)(xb + (size_t)(r + 32) * D_ + kc + c4);
#pragma unroll
        for (int j = 0; j < 4; ++j) {
            As[(c4 + j) * LDT + r]      = a0[j];
            As[(c4 + j) * LDT + r + 32] = a1[j];
            Bs[(c4 + j) * LDT + r]      = b0[j];
            Bs[(c4 + j) * LDT + r + 32] = b1[j];
        }
        __syncthreads();
#pragma unroll
        for (int k = 0; k < KC; ++k) {
            f4 a = *(const f4*)&As[k * LDT + ty * 4];
            f4 b = *(const f4*)&Bs[k * LDT + tx * 4];
#pragma unroll
            for (int i = 0; i < 4; ++i)
#pragma unroll
                for (int j = 0; j < 4; ++j)
                    acc[i][j] = fmaf(a[i], b[j], acc[i][j]);
        }
    }

    float w = (i0 == j0) ? 1.f : 2.f;
    float tot = 0.f;
#pragma unroll
    for (int i = 0; i < 4; ++i) {
        int li = i0 + ty * 4 + i;
        float si = sqx[n * L_ + li];
        float mi = (float)mask[n * L_ + li];
#pragma unroll
        for (int j = 0; j < 4; ++j) {
            int lj = j0 + tx * 4 + j;
            float raw = si + sqx[n * L_ + lj] - 2.f * acc[i][j];
            float d = raw > 0.f ? sqrtf(raw) : 0.f;
            tot += d * mi * (float)mask[n * L_ + lj];
        }
    }
    tot *= w;
#pragma unroll
    for (int off = 32; off; off >>= 1) tot += __shfl_down(tot, off);
    __shared__ float rw[4];
    if ((tid & 63) == 0) rw[tid >> 6] = tot;
    __syncthreads();
    if (tid == 0) atomicAdd(&edq[n], rw[0] + rw[1] + rw[2] + rw[3]);
}

// ---------------- final: scores -> log_softmax -> loss ----------------
__global__ __launch_bounds__(64) void score_kernel(const float* __restrict__ ed_raw,
                                                   const float* __restrict__ edq,
                                                   const float* __restrict__ S,
                                                   float* __restrict__ out) {
    int n = threadIdx.x;  // 0..63
    float Sn = S[n];
    float valid1 = fmaxf(Sn, 1.f);
    float valid2 = fmaxf(Sn * Sn, 1.f);
    float edq_n = edq[n] / valid2;
    float mx = -INFINITY, diag = 0.f;
    for (int m = 0; m < M_; ++m) {
        float sc = -20.f * (2.f * ed_raw[n * M_ + m] / valid1 - edq_n);
        if (m == n) diag = sc;
        mx = fmaxf(mx, sc);
    }
    float se = 0.f;
    for (int m = 0; m < M_; ++m) {
        float sc = -20.f * (2.f * ed_raw[n * M_ + m] / valid1 - edq_n);
        se += expf(sc - mx);
    }
    float lossn = -(diag - (mx + logf(se)));
#pragma unroll
    for (int off = 32; off; off >>= 1) lossn += __shfl_down(lossn, off);
    if (n == 0) out[0] = lossn * (1.f / (float)N_);
}

extern "C" void kernel_launch(void* const* d_in, const int* in_sizes, int n_in,
                              void* d_out, int out_size, void* d_ws, size_t ws_size,
                              hipStream_t stream) {
    const float* x = (const float*)d_in[0];
    const float* y = (const float*)d_in[1];
    const int* mask = (const int*)d_in[2];

    float* ws = (float*)d_ws;
    float* sqx    = ws;              // 16384
    float* sqy    = ws + 16384;      // 128
    float* S      = ws + 16512;      // 64
    float* ed_raw = ws + 16576;      // 8192
    float* edq    = ws + 24768;      // 64  (contiguous with ed_raw)

    hipMemsetAsync(ed_raw, 0, (8192 + 64) * sizeof(float), stream);

    ssq_kernel<<<(N_ * L_) / 4, 256, 0, stream>>>(x, sqx, N_ * L_);
    ssq_kernel<<<M_ / 4, 256, 0, stream>>>(y, sqy, M_);
    masksum_kernel<<<N_, 64, 0, stream>>>(mask, S);

    dim3 gA(M_ / 64, L_ / 64, N_);
    edxy_kernel<<<gA, 256, 0, stream>>>(x, y, sqx, sqy, mask, ed_raw);

    dim3 gB(10, N_);
    edxx_kernel<<<gB, 256, 0, stream>>>(x, sqx, mask, edq);

    score_kernel<<<1, 64, 0, stream>>>(ed_raw, edq, S, (float*)d_out);
}

// Round 2
// 211.244 us; speedup vs baseline: 1.3219x; 1.3219x over previous
//
#include <hip/hip_runtime.h>
#include <math.h>

#define N_ 64
#define L_ 256
#define D_ 1024
#define M_ 128
#define BK 32

typedef float f4 __attribute__((ext_vector_type(4)));
typedef short bf16x8 __attribute__((ext_vector_type(8)));
typedef short s4v __attribute__((ext_vector_type(4)));
typedef float f32x4 __attribute__((ext_vector_type(4)));

// ---------------- fp32 -> bf16 hi/lo split + row sum-of-squares ----------------
__global__ __launch_bounds__(256) void convert_ssq_kernel(const float* __restrict__ in,
                                                          short* __restrict__ hi,
                                                          short* __restrict__ lo,
                                                          float* __restrict__ ssq, int rows) {
    int w = threadIdx.x >> 6, lane = threadIdx.x & 63;
    int row = blockIdx.x * 4 + w;
    if (row >= rows) return;
    const f4* p = (const f4*)(in + (size_t)row * D_);
    float s = 0.f;
#pragma unroll
    for (int rep = 0; rep < 4; ++rep) {
        f4 v = p[rep * 64 + lane];
        s4v h, l;
#pragma unroll
        for (int j = 0; j < 4; ++j) {
            float f = v[j];
            s = fmaf(f, f, s);
            unsigned u = __float_as_uint(f);
            unsigned r = (u + 0x7FFFu + ((u >> 16) & 1u)) >> 16;   // RNE to bf16
            float fh = __uint_as_float(r << 16);
            float fl = f - fh;
            unsigned u2 = __float_as_uint(fl);
            unsigned r2 = (u2 + 0x7FFFu + ((u2 >> 16) & 1u)) >> 16;
            h[j] = (short)r;
            l[j] = (short)r2;
        }
        int e = rep * 256 + lane * 4;
        *(s4v*)(hi + (size_t)row * D_ + e) = h;
        *(s4v*)(lo + (size_t)row * D_ + e) = l;
    }
#pragma unroll
    for (int off = 32; off; off >>= 1) s += __shfl_down(s, off);
    if (lane == 0) ssq[row] = s;
}

// ---------------- mask row sums ----------------
__global__ __launch_bounds__(64) void masksum_kernel(const int* __restrict__ mask,
                                                     float* __restrict__ S) {
    int n = blockIdx.x;
    int lane = threadIdx.x;
    int s = 0;
#pragma unroll
    for (int rep = 0; rep < 4; ++rep) s += mask[n * L_ + rep * 64 + lane];
#pragma unroll
    for (int off = 32; off; off >>= 1) s += __shfl_down(s, off);
    if (lane == 0) S[n] = (float)s;
}

// LDS tile layout: byte = row*64 + (kg ^ ((row>>1)&3))*16  (XOR slot swizzle)
__device__ __forceinline__ int tile_off(int row, int kg) {
    return (row << 6) + ((kg ^ ((row >> 1) & 3)) << 4);
}

// ---------------- fused split-bf16 MFMA GEMM + sqrt/mask epilogue ----------------
// blocks 0..255   : edxy  (A = x[n] 128 rows, B = y 64 rows) -> column sums into ed_raw
// blocks 256..767 : edxx  (A = x[n] 128 rows, B = x[n] 64 rows) -> scalar sum into edq
__global__ __launch_bounds__(256) void ed_mfma_kernel(
        const short* __restrict__ xh, const short* __restrict__ xl,
        const short* __restrict__ yh, const short* __restrict__ yl,
        const float* __restrict__ sqx, const float* __restrict__ sqy,
        const int* __restrict__ mask,
        float* __restrict__ ed_raw, float* __restrict__ edq) {
    __shared__ __align__(16) char lds[24576];  // A_hi 0, A_lo 8192, B_hi 16384, B_lo 20480
    int tid = threadIdx.x;
    int b = blockIdx.x;
    int wid = tid >> 6, lane = tid & 63;
    int wr = wid >> 1, wc = wid & 1;

    int n, l0, c0, mode;
    const short *Ah, *Al, *Bh, *Bl;
    if (b < 256) {
        mode = 0;
        n = b >> 2; int t = b & 3;
        l0 = (t >> 1) << 7; c0 = (t & 1) << 6;
        Bh = yh + (size_t)c0 * D_;
        Bl = yl + (size_t)c0 * D_;
    } else {
        mode = 1;
        int p = b - 256;
        n = p >> 3; int t = p & 7;
        l0 = (t >> 2) << 7; c0 = (t & 3) << 6;
        Bh = xh + ((size_t)n * L_ + c0) * D_;
        Bl = xl + ((size_t)n * L_ + c0) * D_;
    }
    Ah = xh + ((size_t)n * L_ + l0) * D_;
    Al = xl + ((size_t)n * L_ + l0) * D_;

    f32x4 acc[4][2];
#pragma unroll
    for (int i = 0; i < 4; ++i)
#pragma unroll
        for (int j = 0; j < 2; ++j)
            acc[i][j] = (f32x4){0.f, 0.f, 0.f, 0.f};

    int fr = lane & 15, kg = lane >> 4;

#define STAGE(SRC, BASE, DD) do {                                                    \
        int d_ = (DD);                                                               \
        int row_ = d_ >> 2;                                                          \
        int kgs_ = (d_ & 3) ^ ((row_ >> 1) & 3);                                     \
        const short* g_ = (SRC) + (size_t)row_ * D_ + k0 + (kgs_ << 3);              \
        __builtin_amdgcn_global_load_lds(                                            \
            (const __attribute__((address_space(1))) void*)g_,                       \
            (__attribute__((address_space(3))) void*)(lds + (BASE) + ((d_ >> 6) << 10)), \
            16, 0, 0);                                                               \
    } while (0)

    for (int k0 = 0; k0 < D_; k0 += BK) {
        __syncthreads();
        STAGE(Ah, 0, tid);       STAGE(Ah, 0, 256 + tid);
        STAGE(Al, 8192, tid);    STAGE(Al, 8192, 256 + tid);
        STAGE(Bh, 16384, tid);
        STAGE(Bl, 20480, tid);
        __syncthreads();

        bf16x8 ah[4], al[4], bh2[2], bl2[2];
#pragma unroll
        for (int fi = 0; fi < 4; ++fi) {
            int row = (wr << 6) + (fi << 4) + fr;
            ah[fi] = *(const bf16x8*)(lds + tile_off(row, kg));
            al[fi] = *(const bf16x8*)(lds + 8192 + tile_off(row, kg));
        }
#pragma unroll
        for (int fj = 0; fj < 2; ++fj) {
            int col = (wc << 5) + (fj << 4) + fr;
            bh2[fj] = *(const bf16x8*)(lds + 16384 + tile_off(col, kg));
            bl2[fj] = *(const bf16x8*)(lds + 20480 + tile_off(col, kg));
        }
#pragma unroll
        for (int fi = 0; fi < 4; ++fi)
#pragma unroll
            for (int fj = 0; fj < 2; ++fj) {
                acc[fi][fj] = __builtin_amdgcn_mfma_f32_16x16x32_bf16(ah[fi], bh2[fj], acc[fi][fj], 0, 0, 0);
                acc[fi][fj] = __builtin_amdgcn_mfma_f32_16x16x32_bf16(ah[fi], bl2[fj], acc[fi][fj], 0, 0, 0);
                acc[fi][fj] = __builtin_amdgcn_mfma_f32_16x16x32_bf16(al[fi], bh2[fj], acc[fi][fj], 0, 0, 0);
            }
    }
#undef STAGE

    int rbase = (lane >> 4) << 2;

    if (mode == 0) {
        int colg[2];
        float sy[2];
#pragma unroll
        for (int fj = 0; fj < 2; ++fj) {
            colg[fj] = c0 + (wc << 5) + (fj << 4) + fr;
            sy[fj] = sqy[colg[fj]];
        }
        float colsum[2] = {0.f, 0.f};
#pragma unroll
        for (int fi = 0; fi < 4; ++fi) {
#pragma unroll
            for (int r = 0; r < 4; ++r) {
                int gl = l0 + (wr << 6) + (fi << 4) + rbase + r;
                float sx = sqx[n * L_ + gl];
                float mf = (float)mask[n * L_ + gl];
#pragma unroll
                for (int fj = 0; fj < 2; ++fj) {
                    float raw = fmaf(-2.f, acc[fi][fj][r], sx + sy[fj]);
                    float dd = raw > 0.f ? sqrtf(raw) : 0.f;
                    colsum[fj] = fmaf(dd, mf, colsum[fj]);
                }
            }
        }
#pragma unroll
        for (int fj = 0; fj < 2; ++fj) {
            colsum[fj] += __shfl_xor(colsum[fj], 16);
            colsum[fj] += __shfl_xor(colsum[fj], 32);
        }
        if (lane < 16) {
#pragma unroll
            for (int fj = 0; fj < 2; ++fj)
                atomicAdd(&ed_raw[n * M_ + c0 + (wc << 5) + (fj << 4) + lane], colsum[fj]);
        }
    } else {
        int gj[2];
        float sj[2], mj[2];
#pragma unroll
        for (int fj = 0; fj < 2; ++fj) {
            gj[fj] = c0 + (wc << 5) + (fj << 4) + fr;
            sj[fj] = sqx[n * L_ + gj[fj]];
            mj[fj] = (float)mask[n * L_ + gj[fj]];
        }
        float tot = 0.f;
#pragma unroll
        for (int fi = 0; fi < 4; ++fi) {
#pragma unroll
            for (int r = 0; r < 4; ++r) {
                int gl = l0 + (wr << 6) + (fi << 4) + rbase + r;
                float sx = sqx[n * L_ + gl];
                float mf = (float)mask[n * L_ + gl];
#pragma unroll
                for (int fj = 0; fj < 2; ++fj) {
                    float raw = fmaf(-2.f, acc[fi][fj][r], sx + sj[fj]);
                    float dd = raw > 0.f ? sqrtf(raw) : 0.f;
                    if (gl == gj[fj]) dd = 0.f;   // exact-zero diagonal
                    tot = fmaf(dd * mf, mj[fj], tot);
                }
            }
        }
#pragma unroll
        for (int off = 32; off; off >>= 1) tot += __shfl_xor(tot, off);
        if (lane == 0) atomicAdd(&edq[n], tot);
    }
}

// ---------------- final: scores -> log_softmax -> loss ----------------
__global__ __launch_bounds__(64) void score_kernel(const float* __restrict__ ed_raw,
                                                   const float* __restrict__ edq,
                                                   const float* __restrict__ S,
                                                   float* __restrict__ out) {
    int n = threadIdx.x;  // 0..63
    float Sn = S[n];
    float valid1 = fmaxf(Sn, 1.f);
    float valid2 = fmaxf(Sn * Sn, 1.f);
    float edq_n = edq[n] / valid2;
    float mx = -INFINITY, diag = 0.f;
    for (int m = 0; m < M_; ++m) {
        float sc = -20.f * (2.f * ed_raw[n * M_ + m] / valid1 - edq_n);
        if (m == n) diag = sc;
        mx = fmaxf(mx, sc);
    }
    float se = 0.f;
    for (int m = 0; m < M_; ++m) {
        float sc = -20.f * (2.f * ed_raw[n * M_ + m] / valid1 - edq_n);
        se += expf(sc - mx);
    }
    float lossn = -(diag - (mx + logf(se)));
#pragma unroll
    for (int off = 32; off; off >>= 1) lossn += __shfl_down(lossn, off);
    if (n == 0) out[0] = lossn * (1.f / (float)N_);
}

extern "C" void kernel_launch(void* const* d_in, const int* in_sizes, int n_in,
                              void* d_out, int out_size, void* d_ws, size_t ws_size,
                              hipStream_t stream) {
    const float* x = (const float*)d_in[0];
    const float* y = (const float*)d_in[1];
    const int* mask = (const int*)d_in[2];

    char* base = (char*)d_ws;
    float* sqx    = (float*)(base);           // 16384 f
    float* sqy    = (float*)(base + 65536);   // 128 f
    float* S      = (float*)(base + 66048);   // 64 f
    float* ed_raw = (float*)(base + 66304);   // 8192 f
    float* edq    = (float*)(base + 99072);   // 64 f
    short* xh = (short*)(base + (1 << 20));   // 16M shorts
    short* xl = xh + 16777216;
    short* yh = xl + 16777216;                // 128K shorts
    short* yl = yh + 131072;

    hipMemsetAsync(base + 66304, 0, 33024, stream);  // ed_raw + edq

    convert_ssq_kernel<<<4096, 256, 0, stream>>>(x, xh, xl, sqx, N_ * L_);
    convert_ssq_kernel<<<32, 256, 0, stream>>>(y, yh, yl, sqy, M_);
    masksum_kernel<<<N_, 64, 0, stream>>>(mask, S);

    ed_mfma_kernel<<<768, 256, 0, stream>>>(xh, xl, yh, yl, sqx, sqy, mask, ed_raw, edq);

    score_kernel<<<1, 64, 0, stream>>>(ed_raw, edq, S, (float*)d_out);
}

// Round 3
// 149.777 us; speedup vs baseline: 1.8644x; 1.4104x over previous
//
#include <hip/hip_runtime.h>
#include <math.h>

#define N_ 64
#define L_ 256
#define D_ 1024
#define M_ 128
#define BK 64

typedef float f4 __attribute__((ext_vector_type(4)));
typedef short bf16x8 __attribute__((ext_vector_type(8)));
typedef short s8v __attribute__((ext_vector_type(8)));
typedef float f32x4 __attribute__((ext_vector_type(4)));
typedef int i4 __attribute__((ext_vector_type(4)));

// ---------------- fp32 -> bf16 (RNE) + row sum-of-squares ----------------
__global__ __launch_bounds__(256) void convert_ssq_kernel(const float* __restrict__ in,
                                                          short* __restrict__ hi,
                                                          float* __restrict__ ssq, int rows) {
    int w = threadIdx.x >> 6, lane = threadIdx.x & 63;
    int row = blockIdx.x * 4 + w;
    if (row >= rows) return;
    const f4* p = (const f4*)(in + (size_t)row * D_);
    float s = 0.f;
#pragma unroll
    for (int rep = 0; rep < 2; ++rep) {
        f4 v0 = p[rep * 128 + lane * 2];
        f4 v1 = p[rep * 128 + lane * 2 + 1];
        s8v h;
#pragma unroll
        for (int j = 0; j < 4; ++j) {
            float f = v0[j]; s = fmaf(f, f, s);
            unsigned u = __float_as_uint(f);
            h[j] = (short)((u + 0x7FFFu + ((u >> 16) & 1u)) >> 16);
        }
#pragma unroll
        for (int j = 0; j < 4; ++j) {
            float f = v1[j]; s = fmaf(f, f, s);
            unsigned u = __float_as_uint(f);
            h[4 + j] = (short)((u + 0x7FFFu + ((u >> 16) & 1u)) >> 16);
        }
        *(s8v*)(hi + (size_t)row * D_ + rep * 512 + lane * 8) = h;
    }
#pragma unroll
    for (int off = 32; off; off >>= 1) s += __shfl_down(s, off);
    if (lane == 0) ssq[row] = s;
}

// LDS tile layout: row stride 128B (64 bf16), 8 slots of 16B, slot XOR-swizzled by row
__device__ __forceinline__ int swz(int row, int slot) {
    return (row << 7) + (((slot) ^ (row & 7)) << 4);
}

__device__ __forceinline__ void stage_tile(const short* __restrict__ A,
                                           const short* __restrict__ B,
                                           char* lds, int abase, int bbase,
                                           int k0, int tid) {
    int wofs = (tid >> 6) << 10;
    int r8 = tid >> 3;
    int sl = tid & 7;
#pragma unroll
    for (int i = 0; i < 4; ++i) {
        int row = i * 32 + r8;
        int ss = sl ^ (row & 7);
        __builtin_amdgcn_global_load_lds(
            (const __attribute__((address_space(1))) void*)(A + (size_t)row * D_ + k0 + (ss << 3)),
            (__attribute__((address_space(3))) void*)(lds + abase + (i << 12) + wofs),
            16, 0, 0);
    }
#pragma unroll
    for (int i = 0; i < 2; ++i) {
        int row = i * 32 + r8;
        int ss = sl ^ (row & 7);
        __builtin_amdgcn_global_load_lds(
            (const __attribute__((address_space(1))) void*)(B + (size_t)row * D_ + k0 + (ss << 3)),
            (__attribute__((address_space(3))) void*)(lds + bbase + (i << 12) + wofs),
            16, 0, 0);
    }
}

__device__ __forceinline__ void compute_tile(const char* lds, int abase, int bbase,
                                             int wr, int wc, int fr, int kg,
                                             f32x4 acc[4][2]) {
    bf16x8 a[4][2], b[2][2];
#pragma unroll
    for (int fi = 0; fi < 4; ++fi) {
        int row = (wr << 6) + (fi << 4) + fr;
#pragma unroll
        for (int kh = 0; kh < 2; ++kh)
            a[fi][kh] = *(const bf16x8*)(lds + abase + swz(row, (kh << 2) | kg));
    }
#pragma unroll
    for (int fj = 0; fj < 2; ++fj) {
        int col = (wc << 5) + (fj << 4) + fr;
#pragma unroll
        for (int kh = 0; kh < 2; ++kh)
            b[fj][kh] = *(const bf16x8*)(lds + bbase + swz(col, (kh << 2) | kg));
    }
#pragma unroll
    for (int kh = 0; kh < 2; ++kh)
#pragma unroll
        for (int fi = 0; fi < 4; ++fi)
#pragma unroll
            for (int fj = 0; fj < 2; ++fj)
                acc[fi][fj] = __builtin_amdgcn_mfma_f32_16x16x32_bf16(a[fi][kh], b[fj][kh], acc[fi][fj], 0, 0, 0);
}

// ---------------- fused bf16 MFMA GEMM + sqrt/mask epilogue ----------------
// blocks 0..255   : edxy  (A = x[n] 128 rows, B = y 64 rows) -> column sums into ed_raw
// blocks 256..767 : edxx  (A = x[n] 128 rows, B = x[n] 64 rows) -> scalar sum into edq
__global__ __launch_bounds__(256) void ed_mfma_kernel(
        const short* __restrict__ xh, const short* __restrict__ yh,
        const float* __restrict__ sqx, const float* __restrict__ sqy,
        const int* __restrict__ mask,
        float* __restrict__ ed_raw, float* __restrict__ edq) {
    __shared__ __align__(16) char lds[49152];  // [A0 16K][B0 8K][A1 16K][B1 8K]
    int tid = threadIdx.x;
    int b = blockIdx.x;
    int wid = tid >> 6, lane = tid & 63;
    int wr = wid >> 1, wc = wid & 1;

    int n, l0, c0, mode;
    const short *Ah, *Bh;
    if (b < 256) {
        mode = 0;
        n = b >> 2; int t = b & 3;
        l0 = (t >> 1) << 7; c0 = (t & 1) << 6;
        Bh = yh + (size_t)c0 * D_;
    } else {
        mode = 1;
        int p = b - 256;
        n = p >> 3; int t = p & 7;
        l0 = (t >> 2) << 7; c0 = (t & 3) << 6;
        Bh = xh + ((size_t)n * L_ + c0) * D_;
    }
    Ah = xh + ((size_t)n * L_ + l0) * D_;

    f32x4 acc[4][2];
#pragma unroll
    for (int i = 0; i < 4; ++i)
#pragma unroll
        for (int j = 0; j < 2; ++j)
            acc[i][j] = (f32x4){0.f, 0.f, 0.f, 0.f};

    int fr = lane & 15, kg = lane >> 4;

    int buf = 0;
    stage_tile(Ah, Bh, lds, 0, 16384, 0, tid);
    __syncthreads();
    for (int t = 0; t < 15; ++t) {
        int nb = buf ^ 1;
        stage_tile(Ah, Bh, lds, nb * 24576, nb * 24576 + 16384, (t + 1) * BK, tid);
        compute_tile(lds, buf * 24576, buf * 24576 + 16384, wr, wc, fr, kg, acc);
        __syncthreads();
        buf = nb;
    }
    compute_tile(lds, buf * 24576, buf * 24576 + 16384, wr, wc, fr, kg, acc);

    int rbase = (lane >> 4) << 2;

    if (mode == 0) {
        float sy[2];
#pragma unroll
        for (int fj = 0; fj < 2; ++fj)
            sy[fj] = sqy[c0 + (wc << 5) + (fj << 4) + fr];
        float colsum[2] = {0.f, 0.f};
#pragma unroll
        for (int fi = 0; fi < 4; ++fi) {
#pragma unroll
            for (int r = 0; r < 4; ++r) {
                int gl = l0 + (wr << 6) + (fi << 4) + rbase + r;
                float sx = sqx[n * L_ + gl];
                float mf = (float)mask[n * L_ + gl];
#pragma unroll
                for (int fj = 0; fj < 2; ++fj) {
                    float raw = fmaf(-2.f, acc[fi][fj][r], sx + sy[fj]);
                    float dd = raw > 0.f ? sqrtf(raw) : 0.f;
                    colsum[fj] = fmaf(dd, mf, colsum[fj]);
                }
            }
        }
#pragma unroll
        for (int fj = 0; fj < 2; ++fj) {
            colsum[fj] += __shfl_xor(colsum[fj], 16);
            colsum[fj] += __shfl_xor(colsum[fj], 32);
        }
        if (lane < 16) {
#pragma unroll
            for (int fj = 0; fj < 2; ++fj)
                atomicAdd(&ed_raw[n * M_ + c0 + (wc << 5) + (fj << 4) + lane], colsum[fj]);
        }
    } else {
        int gj[2];
        float sj[2], mj[2];
#pragma unroll
        for (int fj = 0; fj < 2; ++fj) {
            gj[fj] = c0 + (wc << 5) + (fj << 4) + fr;
            sj[fj] = sqx[n * L_ + gj[fj]];
            mj[fj] = (float)mask[n * L_ + gj[fj]];
        }
        float tot = 0.f;
#pragma unroll
        for (int fi = 0; fi < 4; ++fi) {
#pragma unroll
            for (int r = 0; r < 4; ++r) {
                int gl = l0 + (wr << 6) + (fi << 4) + rbase + r;
                float sx = sqx[n * L_ + gl];
                float mf = (float)mask[n * L_ + gl];
#pragma unroll
                for (int fj = 0; fj < 2; ++fj) {
                    float raw = fmaf(-2.f, acc[fi][fj][r], sx + sj[fj]);
                    float dd = raw > 0.f ? sqrtf(raw) : 0.f;
                    if (gl == gj[fj]) dd = 0.f;   // exact-zero diagonal
                    tot = fmaf(dd * mf, mj[fj], tot);
                }
            }
        }
#pragma unroll
        for (int off = 32; off; off >>= 1) tot += __shfl_xor(tot, off);
        if (lane == 0) atomicAdd(&edq[n], tot);
    }
}

// ---------------- final: mask sums + scores -> log_softmax -> loss ----------------
__global__ __launch_bounds__(256) void score_kernel(const float* __restrict__ ed_raw,
                                                    const float* __restrict__ edq,
                                                    const int* __restrict__ mask,
                                                    float* __restrict__ out) {
    __shared__ float sc[N_ * M_];   // 32 KB
    __shared__ float Ssh[N_];
    __shared__ float red[N_];
    int tid = threadIdx.x;
    {   // mask sums: thread t sums 64 consecutive ints; 4 threads per n
        const i4* mp = (const i4*)(mask + tid * 64);
        int s = 0;
#pragma unroll
        for (int i = 0; i < 16; ++i) { i4 v = mp[i]; s += v[0] + v[1] + v[2] + v[3]; }
        s += __shfl_xor(s, 1);
        s += __shfl_xor(s, 2);
        if ((tid & 3) == 0) Ssh[tid >> 2] = (float)s;
    }
    __syncthreads();
    for (int i = tid; i < N_ * M_; i += 256) {
        int n = i >> 7;
        float Sn = Ssh[n];
        float valid1 = fmaxf(Sn, 1.f);
        float edq_n = edq[n] / fmaxf(Sn * Sn, 1.f);
        sc[i] = -20.f * (2.f * ed_raw[i] / valid1 - edq_n);
    }
    __syncthreads();
    int n = tid >> 2, q = tid & 3;
    const float* row = sc + n * M_;
    float mx = -INFINITY;
    for (int m = q * 32; m < q * 32 + 32; ++m) mx = fmaxf(mx, row[m]);
    mx = fmaxf(mx, __shfl_xor(mx, 1));
    mx = fmaxf(mx, __shfl_xor(mx, 2));
    float se = 0.f;
    for (int m = q * 32; m < q * 32 + 32; ++m) se += expf(row[m] - mx);
    se += __shfl_xor(se, 1);
    se += __shfl_xor(se, 2);
    if (q == 0) red[n] = -(row[n] - mx - logf(se));
    __syncthreads();
    if (tid < 64) {
        float v = red[tid];
#pragma unroll
        for (int off = 32; off; off >>= 1) v += __shfl_down(v, off);
        if (tid == 0) out[0] = v * (1.f / (float)N_);
    }
}

extern "C" void kernel_launch(void* const* d_in, const int* in_sizes, int n_in,
                              void* d_out, int out_size, void* d_ws, size_t ws_size,
                              hipStream_t stream) {
    const float* x = (const float*)d_in[0];
    const float* y = (const float*)d_in[1];
    const int* mask = (const int*)d_in[2];

    char* base = (char*)d_ws;
    float* sqx    = (float*)(base);           // 16384 f
    float* sqy    = (float*)(base + 65536);   // 128 f
    float* ed_raw = (float*)(base + 66048);   // 8192 f
    float* edq    = (float*)(base + 98816);   // 64 f
    short* xh = (short*)(base + (1 << 20));   // 16.78M shorts
    short* yh = xh + 16777216;                // 131072 shorts

    hipMemsetAsync(base + 66048, 0, 33024, stream);  // ed_raw + edq

    convert_ssq_kernel<<<4096, 256, 0, stream>>>(x, xh, sqx, N_ * L_);
    convert_ssq_kernel<<<32, 256, 0, stream>>>(y, yh, sqy, M_);

    ed_mfma_kernel<<<768, 256, 0, stream>>>(xh, yh, sqx, sqy, mask, ed_raw, edq);

    score_kernel<<<1, 256, 0, stream>>>(ed_raw, edq, mask, (float*)d_out);
}

// Round 5
// 138.474 us; speedup vs baseline: 2.0166x; 1.0816x over previous
//
#include <hip/hip_runtime.h>
#include <math.h>

#define N_ 64
#define L_ 256
#define D_ 1024
#define M_ 128
#define BK 64

typedef float f4 __attribute__((ext_vector_type(4)));
typedef short bf16x8 __attribute__((ext_vector_type(8)));
typedef short s8v __attribute__((ext_vector_type(8)));
typedef float f32x4 __attribute__((ext_vector_type(4)));
typedef int i4 __attribute__((ext_vector_type(4)));

// ---------------- fp32 -> bf16 (RNE) + row sum-of-squares (x and y fused) ----------------
// blocks 0..4095: x rows (4/block). blocks 4096..4127: y rows.
__global__ __launch_bounds__(256) void convert_ssq_kernel(const float* __restrict__ x,
                                                          const float* __restrict__ y,
                                                          short* __restrict__ xh,
                                                          short* __restrict__ yh,
                                                          float* __restrict__ sqx,
                                                          float* __restrict__ sqy) {
    int w = threadIdx.x >> 6, lane = threadIdx.x & 63;
    int row = blockIdx.x * 4 + w;
    const float* in;
    short* hi;
    float* ssq;
    int r;
    if (row < N_ * L_) { in = x; hi = xh; ssq = sqx; r = row; }
    else               { in = y; hi = yh; ssq = sqy; r = row - N_ * L_; }
    const f4* p = (const f4*)(in + (size_t)r * D_);
    float s = 0.f;
#pragma unroll
    for (int rep = 0; rep < 2; ++rep) {
        f4 v0 = p[rep * 128 + lane * 2];
        f4 v1 = p[rep * 128 + lane * 2 + 1];
        s8v h;
#pragma unroll
        for (int j = 0; j < 4; ++j) {
            float f = v0[j]; s = fmaf(f, f, s);
            unsigned u = __float_as_uint(f);
            h[j] = (short)((u + 0x7FFFu + ((u >> 16) & 1u)) >> 16);
        }
#pragma unroll
        for (int j = 0; j < 4; ++j) {
            float f = v1[j]; s = fmaf(f, f, s);
            unsigned u = __float_as_uint(f);
            h[4 + j] = (short)((u + 0x7FFFu + ((u >> 16) & 1u)) >> 16);
        }
        *(s8v*)(hi + (size_t)r * D_ + rep * 512 + lane * 8) = h;
    }
#pragma unroll
    for (int off = 32; off; off >>= 1) s += __shfl_down(s, off);
    if (lane == 0) ssq[r] = s;
}

// LDS tile layout: row stride 128B (64 bf16), 8 slots of 16B, slot XOR-swizzled by row
__device__ __forceinline__ int swz(int row, int slot) {
    return (row << 7) + (((slot) ^ (row & 7)) << 4);
}

__device__ __forceinline__ void stage_tile(const short* __restrict__ A,
                                           const short* __restrict__ B,
                                           char* lds, int abase, int bbase,
                                           int k0, int tid) {
    int wofs = (tid >> 6) << 10;
    int r8 = tid >> 3;
    int sl = tid & 7;
#pragma unroll
    for (int i = 0; i < 4; ++i) {
        int row = i * 32 + r8;
        int ss = sl ^ (row & 7);
        __builtin_amdgcn_global_load_lds(
            (const __attribute__((address_space(1))) void*)(A + (size_t)row * D_ + k0 + (ss << 3)),
            (__attribute__((address_space(3))) void*)(lds + abase + (i << 12) + wofs),
            16, 0, 0);
    }
#pragma unroll
    for (int i = 0; i < 2; ++i) {
        int row = i * 32 + r8;
        int ss = sl ^ (row & 7);
        __builtin_amdgcn_global_load_lds(
            (const __attribute__((address_space(1))) void*)(B + (size_t)row * D_ + k0 + (ss << 3)),
            (__attribute__((address_space(3))) void*)(lds + bbase + (i << 12) + wofs),
            16, 0, 0);
    }
}

__device__ __forceinline__ void compute_tile(const char* lds, int abase, int bbase,
                                             int wr, int wc, int fr, int kg,
                                             f32x4 acc[4][2]) {
    bf16x8 a[4][2], b[2][2];
#pragma unroll
    for (int fi = 0; fi < 4; ++fi) {
        int row = (wr << 6) + (fi << 4) + fr;
#pragma unroll
        for (int kh = 0; kh < 2; ++kh)
            a[fi][kh] = *(const bf16x8*)(lds + abase + swz(row, (kh << 2) | kg));
    }
#pragma unroll
    for (int fj = 0; fj < 2; ++fj) {
        int col = (wc << 5) + (fj << 4) + fr;
#pragma unroll
        for (int kh = 0; kh < 2; ++kh)
            b[fj][kh] = *(const bf16x8*)(lds + bbase + swz(col, (kh << 2) | kg));
    }
#pragma unroll
    for (int kh = 0; kh < 2; ++kh)
#pragma unroll
        for (int fi = 0; fi < 4; ++fi)
#pragma unroll
            for (int fj = 0; fj < 2; ++fj)
                acc[fi][fj] = __builtin_amdgcn_mfma_f32_16x16x32_bf16(a[fi][kh], b[fj][kh], acc[fi][fj], 0, 0, 0);
}

// ---------------- fused bf16 MFMA GEMM + sqrt/mask epilogue ----------------
// XCD-aware mapping: block b runs on XCD b%8 (round-robin dispatch). XCD x owns
// n in [8x, 8x+8); per n, 12 consecutive slots: 4 edxy tiles then 8 edxx tiles.
// Per-XCD working set ~4.25 MB bf16 ~= one L2.
__global__ __launch_bounds__(256) void ed_mfma_kernel(
        const short* __restrict__ xh, const short* __restrict__ yh,
        const float* __restrict__ sqx, const float* __restrict__ sqy,
        const int* __restrict__ mask,
        float* __restrict__ ed_raw, float* __restrict__ edq) {
    __shared__ __align__(16) char lds[49152];  // [A0 16K][B0 8K][A1 16K][B1 8K]
    int tid = threadIdx.x;
    int b = blockIdx.x;
    int wid = tid >> 6, lane = tid & 63;
    int wr = wid >> 1, wc = wid & 1;

    int xcd = b & 7;
    int slot = b >> 3;            // 0..95
    int n = xcd * 8 + slot / 12;
    int r = slot % 12;

    int l0, c0, mode;
    const short *Ah, *Bh;
    if (r < 4) {
        mode = 0;
        l0 = (r >> 1) << 7; c0 = (r & 1) << 6;
        Bh = yh + (size_t)c0 * D_;
    } else {
        mode = 1;
        int rr = r - 4;
        l0 = (rr >> 2) << 7; c0 = (rr & 3) << 6;
        Bh = xh + ((size_t)n * L_ + c0) * D_;
    }
    Ah = xh + ((size_t)n * L_ + l0) * D_;

    f32x4 acc[4][2];
#pragma unroll
    for (int i = 0; i < 4; ++i)
#pragma unroll
        for (int j = 0; j < 2; ++j)
            acc[i][j] = (f32x4){0.f, 0.f, 0.f, 0.f};

    int fr = lane & 15, kg = lane >> 4;

    int buf = 0;
    stage_tile(Ah, Bh, lds, 0, 16384, 0, tid);
    __syncthreads();
    for (int t = 0; t < 15; ++t) {
        int nb = buf ^ 1;
        stage_tile(Ah, Bh, lds, nb * 24576, nb * 24576 + 16384, (t + 1) * BK, tid);
        compute_tile(lds, buf * 24576, buf * 24576 + 16384, wr, wc, fr, kg, acc);
        __syncthreads();
        buf = nb;
    }
    compute_tile(lds, buf * 24576, buf * 24576 + 16384, wr, wc, fr, kg, acc);

    int rbase = (lane >> 4) << 2;

    if (mode == 0) {
        float sy[2];
#pragma unroll
        for (int fj = 0; fj < 2; ++fj)
            sy[fj] = sqy[c0 + (wc << 5) + (fj << 4) + fr];
        float colsum[2] = {0.f, 0.f};
#pragma unroll
        for (int fi = 0; fi < 4; ++fi) {
#pragma unroll
            for (int rr = 0; rr < 4; ++rr) {
                int gl = l0 + (wr << 6) + (fi << 4) + rbase + rr;
                float sx = sqx[n * L_ + gl];
                float mf = (float)mask[n * L_ + gl];
#pragma unroll
                for (int fj = 0; fj < 2; ++fj) {
                    float raw = fmaf(-2.f, acc[fi][fj][rr], sx + sy[fj]);
                    float dd = raw > 0.f ? sqrtf(raw) : 0.f;
                    colsum[fj] = fmaf(dd, mf, colsum[fj]);
                }
            }
        }
#pragma unroll
        for (int fj = 0; fj < 2; ++fj) {
            colsum[fj] += __shfl_xor(colsum[fj], 16);
            colsum[fj] += __shfl_xor(colsum[fj], 32);
        }
        if (lane < 16) {
#pragma unroll
            for (int fj = 0; fj < 2; ++fj)
                atomicAdd(&ed_raw[n * M_ + c0 + (wc << 5) + (fj << 4) + lane], colsum[fj]);
        }
    } else {
        int gj[2];
        float sj[2], mj[2];
#pragma unroll
        for (int fj = 0; fj < 2; ++fj) {
            gj[fj] = c0 + (wc << 5) + (fj << 4) + fr;
            sj[fj] = sqx[n * L_ + gj[fj]];
            mj[fj] = (float)mask[n * L_ + gj[fj]];
        }
        float tot = 0.f;
#pragma unroll
        for (int fi = 0; fi < 4; ++fi) {
#pragma unroll
            for (int rr = 0; rr < 4; ++rr) {
                int gl = l0 + (wr << 6) + (fi << 4) + rbase + rr;
                float sx = sqx[n * L_ + gl];
                float mf = (float)mask[n * L_ + gl];
#pragma unroll
                for (int fj = 0; fj < 2; ++fj) {
                    float raw = fmaf(-2.f, acc[fi][fj][rr], sx + sj[fj]);
                    float dd = raw > 0.f ? sqrtf(raw) : 0.f;
                    if (gl == gj[fj]) dd = 0.f;   // exact-zero diagonal
                    tot = fmaf(dd * mf, mj[fj], tot);
                }
            }
        }
#pragma unroll
        for (int off = 32; off; off >>= 1) tot += __shfl_xor(tot, off);
        if (lane == 0) atomicAdd(&edq[n], tot);
    }
}

// ---------------- final: mask sums + scores -> log_softmax -> loss ----------------
__global__ __launch_bounds__(256) void score_kernel(const float* __restrict__ ed_raw,
                                                    const float* __restrict__ edq,
                                                    const int* __restrict__ mask,
                                                    float* __restrict__ out) {
    __shared__ float sc[N_ * M_];   // 32 KB
    __shared__ float Ssh[N_];
    __shared__ float red[N_];
    int tid = threadIdx.x;
    {   // mask sums: thread t sums 64 consecutive ints; 4 threads per n
        const i4* mp = (const i4*)(mask + tid * 64);
        int s = 0;
#pragma unroll
        for (int i = 0; i < 16; ++i) { i4 v = mp[i]; s += v[0] + v[1] + v[2] + v[3]; }
        s += __shfl_xor(s, 1);
        s += __shfl_xor(s, 2);
        if ((tid & 3) == 0) Ssh[tid >> 2] = (float)s;
    }
    __syncthreads();
    for (int i = tid; i < N_ * M_; i += 256) {
        int n = i >> 7;
        float Sn = Ssh[n];
        float valid1 = fmaxf(Sn, 1.f);
        float edq_n = edq[n] / fmaxf(Sn * Sn, 1.f);
        sc[i] = -20.f * (2.f * ed_raw[i] / valid1 - edq_n);
    }
    __syncthreads();
    int n = tid >> 2, q = tid & 3;
    const float* row = sc + n * M_;
    float mx = -INFINITY;
    for (int m = q * 32; m < q * 32 + 32; ++m) mx = fmaxf(mx, row[m]);
    mx = fmaxf(mx, __shfl_xor(mx, 1));
    mx = fmaxf(mx, __shfl_xor(mx, 2));
    float se = 0.f;
    for (int m = q * 32; m < q * 32 + 32; ++m) se += expf(row[m] - mx);
    se += __shfl_xor(se, 1);
    se += __shfl_xor(se, 2);
    if (q == 0) red[n] = -(row[n] - mx - logf(se));
    __syncthreads();
    if (tid < 64) {
        float v = red[tid];
#pragma unroll
        for (int off = 32; off; off >>= 1) v += __shfl_down(v, off);
        if (tid == 0) out[0] = v * (1.f / (float)N_);
    }
}

extern "C" void kernel_launch(void* const* d_in, const int* in_sizes, int n_in,
                              void* d_out, int out_size, void* d_ws, size_t ws_size,
                              hipStream_t stream) {
    const float* x = (const float*)d_in[0];
    const float* y = (const float*)d_in[1];
    const int* mask = (const int*)d_in[2];

    char* base = (char*)d_ws;
    float* sqx    = (float*)(base);           // 16384 f
    float* sqy    = (float*)(base + 65536);   // 128 f
    float* ed_raw = (float*)(base + 66048);   // 8192 f
    float* edq    = (float*)(base + 98816);   // 64 f
    short* xh = (short*)(base + (1 << 20));   // 16.78M shorts
    short* yh = xh + 16777216;                // 131072 shorts

    hipMemsetAsync(base + 66048, 0, 33024, stream);  // ed_raw + edq

    convert_ssq_kernel<<<(N_ * L_ + M_) / 4, 256, 0, stream>>>(x, y, xh, yh, sqx, sqy);

    ed_mfma_kernel<<<768, 256, 0, stream>>>(xh, yh, sqx, sqy, mask, ed_raw, edq);

    score_kernel<<<1, 256, 0, stream>>>(ed_raw, edq, mask, (float*)d_out);
}